// Round 4
// baseline (7204.658 us; speedup 1.0000x reference)
//
#include <hip/hip_runtime.h>
#include <stdint.h>

typedef __bf16 bf16;
typedef __attribute__((ext_vector_type(8))) __bf16 bf16x8;
typedef __attribute__((ext_vector_type(4))) float floatx4;

__device__ inline float bflo(uint32_t u){ union{uint32_t v; float f;} t; t.v = u << 16; return t.f; }
__device__ inline float bfhi(uint32_t u){ union{uint32_t v; float f;} t; t.v = u & 0xffff0000u; return t.f; }
__device__ inline uint32_t pack2(float a, float b){ union{ bf16 h[2]; uint32_t u; } t; t.h[0]=(bf16)a; t.h[1]=(bf16)b; return t.u; }

__device__ inline void load4(const bf16* p, float* x){
  uint2 u = *(const uint2*)p; x[0]=bflo(u.x); x[1]=bfhi(u.x); x[2]=bflo(u.y); x[3]=bfhi(u.y);
}
__device__ inline void load4(const float* p, float* x){
  float4 u = *(const float4*)p; x[0]=u.x; x[1]=u.y; x[2]=u.z; x[3]=u.w;
}

// ---------------- LayerNorm (row-per-block, width W). In-place safe (row loaded to regs first). ----------------
template<int W, typename TIN>
__global__ __launch_bounds__(256) void ln_kernel(const TIN* in, const float* __restrict__ g,
                                                 const float* __restrict__ bb, bf16* out, int M)
{
  constexpr int E = W / 256;
  int row = blockIdx.x; if (row >= M) return;
  int tid = threadIdx.x;
  const TIN* rp = in + (size_t)row * W + tid * E;
  float x[E];
  #pragma unroll
  for (int j = 0; j < E; j += 4) load4(rp + j, &x[j]);
  float s = 0.f, ss = 0.f;
  #pragma unroll
  for (int e = 0; e < E; e++){ s += x[e]; ss += x[e]*x[e]; }
  #pragma unroll
  for (int k = 32; k >= 1; k >>= 1){ s += __shfl_xor(s, k, 64); ss += __shfl_xor(ss, k, 64); }
  __shared__ float rs_[4], rq_[4];
  if ((tid & 63) == 0){ rs_[tid >> 6] = s; rq_[tid >> 6] = ss; }
  __syncthreads();
  s = rs_[0]+rs_[1]+rs_[2]+rs_[3]; ss = rq_[0]+rq_[1]+rq_[2]+rq_[3];
  float mean = s * (1.0f / W);
  float var  = ss * (1.0f / W) - mean * mean;
  float rinv = rsqrtf(var + 1e-5f);
  bf16* op = out + (size_t)row * W + tid * E;
  const float* gp = g + tid * E;
  const float* bp = bb + tid * E;
  #pragma unroll
  for (int j = 0; j < E; j += 4){
    float gv[4], bv[4];
    load4(gp + j, gv); load4(bp + j, bv);
    float y0 = (x[j]  -mean)*rinv*gv[0] + bv[0];
    float y1 = (x[j+1]-mean)*rinv*gv[1] + bv[1];
    float y2 = (x[j+2]-mean)*rinv*gv[2] + bv[2];
    float y3 = (x[j+3]-mean)*rinv*gv[3] + bv[3];
    uint2 o; o.x = pack2(y0, y1); o.y = pack2(y2, y3);
    *(uint2*)(op + j) = o;
  }
}

// ---------------- NT GEMM: C[M,N] = A[M,K](bf16) @ B[N,K]^T(f32->bf16) + bias(f32), fused epilogues ----------------
// mode 0: +bias ; mode 1: +bias+extra[m,n] ; mode 2: silu(extra[m,n]) * (acc+bias)   [extra may alias C]
template<typename TE, typename TC>
__global__ __launch_bounds__(256) void gemm_bt(const bf16* __restrict__ A, const float* __restrict__ Bw,
                                               const float* __restrict__ bias, const TE* extra,
                                               TC* C, int M, int N, int K, int mode)
{
  __shared__ __align__(16) bf16 As[128*32];
  __shared__ __align__(16) bf16 Bs[128*32];
  int tid = threadIdx.x;
  int lane = tid & 63, wave = tid >> 6;
  int l16 = lane & 15, quad = lane >> 4;
  int wm = wave >> 1, wn = wave & 1;
  int m0 = blockIdx.y * 128, n0 = blockIdx.x * 128;
  floatx4 acc[4][4];
  #pragma unroll
  for (int i = 0; i < 4; i++)
    #pragma unroll
    for (int j = 0; j < 4; j++) acc[i][j] = (floatx4){0.f,0.f,0.f,0.f};
  int nk = K >> 5;
  uint4 ar[2];
  float4 br0[2], br1[2];
  int rowA[2], colA[2];
  #pragma unroll
  for (int rr = 0; rr < 2; rr++){ int lin = rr*256 + tid; rowA[rr] = lin >> 2; colA[rr] = (lin & 3) * 8; }
  auto prefetch = [&](int kt){
    #pragma unroll
    for (int rr = 0; rr < 2; rr++){
      size_t ka = (size_t)min(m0 + rowA[rr], M-1) * K + kt*32 + colA[rr];
      ar[rr] = *(const uint4*)(A + ka);
      const float* bp = Bw + (size_t)min(n0 + rowA[rr], N-1) * K + kt*32 + colA[rr];
      br0[rr] = *(const float4*)(bp);
      br1[rr] = *(const float4*)(bp + 4);
    }
  };
  prefetch(0);
  int kt = 0;
  while (true){
    __syncthreads();
    #pragma unroll
    for (int rr = 0; rr < 2; rr++){
      *(uint4*)&As[rowA[rr]*32 + colA[rr]] = ar[rr];
      union { uint4 q; bf16 h[8]; } pk;
      pk.h[0]=(bf16)br0[rr].x; pk.h[1]=(bf16)br0[rr].y; pk.h[2]=(bf16)br0[rr].z; pk.h[3]=(bf16)br0[rr].w;
      pk.h[4]=(bf16)br1[rr].x; pk.h[5]=(bf16)br1[rr].y; pk.h[6]=(bf16)br1[rr].z; pk.h[7]=(bf16)br1[rr].w;
      *(uint4*)&Bs[rowA[rr]*32 + colA[rr]] = pk.q;
    }
    __syncthreads();
    ++kt;
    bool more = kt < nk;
    if (more) prefetch(kt);
    bf16x8 af[4], bfv[4];
    #pragma unroll
    for (int i = 0; i < 4; i++) af[i]  = *(const bf16x8*)&As[(wm*64 + i*16 + l16)*32 + quad*8];
    #pragma unroll
    for (int j = 0; j < 4; j++) bfv[j] = *(const bf16x8*)&Bs[(wn*64 + j*16 + l16)*32 + quad*8];
    #pragma unroll
    for (int i = 0; i < 4; i++)
      #pragma unroll
      for (int j = 0; j < 4; j++)
        acc[i][j] = __builtin_amdgcn_mfma_f32_16x16x32_bf16(af[i], bfv[j], acc[i][j], 0, 0, 0);
    if (!more) break;
  }
  #pragma unroll
  for (int i = 0; i < 4; i++){
    int gmb = m0 + wm*64 + i*16 + quad*4;
    #pragma unroll
    for (int j = 0; j < 4; j++){
      int gn = n0 + wn*64 + j*16 + l16;
      float bv = bias ? bias[gn] : 0.f;
      #pragma unroll
      for (int r = 0; r < 4; r++){
        int gm = gmb + r;
        if (gm < M){
          float v = acc[i][j][r] + bv;
          if (mode == 1) v += (float)extra[(size_t)gm * N + gn];
          else if (mode == 2){ float a = (float)extra[(size_t)gm * N + gn]; v *= a / (1.f + __expf(-a)); }
          C[(size_t)gm * N + gn] = (TC)v;
        }
      }
    }
  }
}

// ---------------- RoPE (in-place on q and k buffers (bf16), tokens 1..256, all dims) ----------------
__global__ __launch_bounds__(256) void rope_kernel(bf16* __restrict__ q, bf16* __restrict__ k,
                                                   const float* __restrict__ cs, const float* __restrict__ sn)
{
  uint32_t i = blockIdx.x * 256u + threadIdx.x;   // 64*256*512 pairs
  int d0 = (int)(i & 511) * 2;
  int tok = (int)((i >> 9) & 255);
  int b = (int)(i >> 17);
  int j = d0 & 63;                                // dim within 64-wide head
  float c0 = cs[tok*64 + j], c1 = cs[tok*64 + j + 1];
  float s0 = sn[tok*64 + j], s1 = sn[tok*64 + j + 1];
  size_t off = ((size_t)(b*257 + tok + 1)) * 1024 + d0;
  uint32_t uq = *(const uint32_t*)(q + off);
  float x0 = bflo(uq), x1 = bfhi(uq);
  *(uint32_t*)(q + off) = pack2(x0*c0 - x1*s0, x1*c1 + x0*s1);
  uint32_t uk = *(const uint32_t*)(k + off);
  float y0 = bflo(uk), y1 = bfhi(uk);
  *(uint32_t*)(k + off) = pack2(y0*c0 - y1*s0, y1*c1 + y0*s1);
}

// ---------------- attention (simple build): one block per (b,h,q-row), plain softmax ----------------
__global__ __launch_bounds__(256) void attn_simple(const bf16* __restrict__ Q, const bf16* __restrict__ Kg,
                                                   const bf16* __restrict__ Vg, const float* __restrict__ tab,
                                                   bf16* __restrict__ AO)
{
  __shared__ float qs[64];
  __shared__ float S[257];
  __shared__ float redm[4], redl[4];
  __shared__ float pvp[4][64];
  int id = blockIdx.x;                  // ((b*16 + h)*257 + qtok)
  int qg = id % 257; int rest = id / 257;
  int h = rest & 15; int b = rest >> 4;
  int tid = threadIdx.x; int wave = tid >> 6; int lane = tid & 63;
  size_t base = ((size_t)b * 257) * 1024 + h * 64;
  if (tid < 32){
    uint32_t u = *(const uint32_t*)(Q + base + (size_t)qg*1024 + tid*2);
    qs[tid*2] = bflo(u); qs[tid*2+1] = bfhi(u);
  }
  __syncthreads();
  // scores: thread t owns keys kk = t, t+256
  for (int kk = tid; kk < 257; kk += 256){
    const bf16* kp = Kg + base + (size_t)kk*1024;
    float acc = 0.f;
    #pragma unroll
    for (int j = 0; j < 64; j += 8){
      uint4 u = *(const uint4*)(kp + j);
      acc += qs[j+0]*bflo(u.x) + qs[j+1]*bfhi(u.x)
           + qs[j+2]*bflo(u.y) + qs[j+3]*bfhi(u.y)
           + qs[j+4]*bflo(u.z) + qs[j+5]*bfhi(u.z)
           + qs[j+6]*bflo(u.w) + qs[j+7]*bfhi(u.w);
    }
    int idx;
    if (qg == 0 && kk == 0) idx = 963;
    else if (qg == 0) idx = 961;
    else if (kk == 0) idx = 962;
    else { int p = qg - 1, pk = kk - 1;
           idx = ((p >> 4) - (pk >> 4) + 15) * 31 + ((p & 15) - (pk & 15) + 15); }
    S[kk] = acc * 0.125f + tab[idx*16 + h];
  }
  __syncthreads();
  // max
  float m = -1e30f;
  for (int kk = tid; kk < 257; kk += 256) m = fmaxf(m, S[kk]);
  #pragma unroll
  for (int k = 32; k >= 1; k >>= 1) m = fmaxf(m, __shfl_xor(m, k, 64));
  if (lane == 0) redm[wave] = m;
  __syncthreads();
  m = fmaxf(fmaxf(redm[0], redm[1]), fmaxf(redm[2], redm[3]));
  // exp + sum (each thread overwrites only its own S entries)
  float sl = 0.f;
  for (int kk = tid; kk < 257; kk += 256){ float p = __expf(S[kk] - m); S[kk] = p; sl += p; }
  #pragma unroll
  for (int k = 32; k >= 1; k >>= 1) sl += __shfl_xor(sl, k, 64);
  if (lane == 0) redl[wave] = sl;
  __syncthreads();                       // also publishes S = p
  float l = redl[0]+redl[1]+redl[2]+redl[3];
  // PV: wave w covers keys w, w+4, ... ; dim = lane
  float acc = 0.f;
  for (int kk = wave; kk < 257; kk += 4)
    acc += S[kk] * (float)Vg[base + (size_t)kk*1024 + lane];
  pvp[wave][lane] = acc;
  __syncthreads();
  if (tid < 64){
    float tot = pvp[0][tid]+pvp[1][tid]+pvp[2][tid]+pvp[3][tid];
    AO[base + (size_t)qg*1024 + tid] = (bf16)(tot / l);
  }
}

extern "C" void kernel_launch(void* const* d_in, const int* in_sizes, int n_in,
                              void* d_out, int out_size, void* d_ws, size_t ws_size,
                              hipStream_t stream)
{
  (void)in_sizes; (void)n_in; (void)out_size; (void)ws_size;
  const float* x    = (const float*)d_in[0];
  const float* rc   = (const float*)d_in[1];
  const float* rsn  = (const float*)d_in[2];
  const float* q_w  = (const float*)d_in[3];
  const float* q_b  = (const float*)d_in[4];
  const float* k_w  = (const float*)d_in[5];
  const float* v_w  = (const float*)d_in[6];
  const float* v_b  = (const float*)d_in[7];
  const float* tab  = (const float*)d_in[8];
  const float* ig   = (const float*)d_in[9];
  const float* ib   = (const float*)d_in[10];
  const float* pw   = (const float*)d_in[11];
  const float* pb   = (const float*)d_in[12];
  const float* n1g  = (const float*)d_in[13];
  const float* n1b  = (const float*)d_in[14];
  const float* n2g  = (const float*)d_in[15];
  const float* n2b  = (const float*)d_in[16];
  const float* w1w  = (const float*)d_in[17];
  const float* w1b  = (const float*)d_in[18];
  const float* w2w  = (const float*)d_in[19];
  const float* w2b  = (const float*)d_in[20];
  const float* fg   = (const float*)d_in[21];
  const float* fb   = (const float*)d_in[22];
  const float* w3w  = (const float*)d_in[23];
  const float* w3b  = (const float*)d_in[24];

  const int M = 64 * 257;        // 16448
  const int D = 1024, HD = 4096;
  char* ws = (char*)d_ws;
  const size_t CHB = (size_t)M * D * 2;          // 33,685,504 B (bf16 channel buffer)
  // total ws used: 4*CHB = 134,742,016 B
  bf16* B0 = (bf16*)(ws);
  bf16* B1 = (bf16*)(ws + CHB);
  bf16* B2 = (bf16*)(ws + 2*CHB);
  bf16* B3 = (bf16*)(ws + 3*CHB);
  bf16* XN  = B0;          // LN1 out
  bf16* Qb  = B1;
  bf16* Kbf = B2;
  bf16* Vbf = B3;
  bf16* AO  = B0;          // XN dead after V GEMM
  bf16* AOL = B1;          // Q dead after attention
  bf16* X1  = B2;          // K dead after attention
  bf16* XN2 = B3;          // V dead after LN2
  bf16* HS  = B0;          // 2*CHB region (B0+B1): AO/AOL dead — per-FFN-chunk hidden
  float* OUT = (float*)d_out;

  dim3 blk(256);
  dim3 g1(D/128, (M + 127)/128);

  ln_kernel<1024, float><<<dim3(M), blk, 0, stream>>>(x, n1g, n1b, XN, M);
  gemm_bt<bf16, bf16><<<g1, blk, 0, stream>>>(XN, q_w, q_b, (const bf16*)nullptr, Qb, M, D, D, 0);
  gemm_bt<bf16, bf16><<<g1, blk, 0, stream>>>(XN, k_w, nullptr, (const bf16*)nullptr, Kbf, M, D, D, 0);
  gemm_bt<bf16, bf16><<<g1, blk, 0, stream>>>(XN, v_w, v_b, (const bf16*)nullptr, Vbf, M, D, D, 0);
  rope_kernel<<<dim3(64*256*512/256), blk, 0, stream>>>(Qb, Kbf, rc, rsn);
  attn_simple<<<dim3(64*16*257), blk, 0, stream>>>(Qb, Kbf, Vbf, tab, AO);
  ln_kernel<1024, bf16><<<dim3(M), blk, 0, stream>>>(AO, ig, ib, AOL, M);
  gemm_bt<float, bf16><<<g1, blk, 0, stream>>>(AOL, pw, pb, x, X1, M, D, D, 1);
  ln_kernel<1024, bf16><<<dim3(M), blk, 0, stream>>>(X1, n2g, n2b, XN2, M);

  // FFN in two M/2 row-chunks so hidden fits in 2*CHB
  const int MC = M / 2;                       // 8224
  dim3 g2(HD/128, (MC + 127)/128);
  dim3 g1c(D/128, (MC + 127)/128);
  for (int c = 0; c < 2; c++){
    const bf16* a2 = XN2 + (size_t)c * MC * D;
    const bf16* x1 = X1  + (size_t)c * MC * D;
    float*      oc = OUT + (size_t)c * MC * D;
    gemm_bt<bf16, bf16><<<g2, blk, 0, stream>>>(a2, w1w, w1b, (const bf16*)nullptr, HS, MC, HD, D, 0);
    gemm_bt<bf16, bf16><<<g2, blk, 0, stream>>>(a2, w2w, w2b, HS, HS, MC, HD, D, 2);
    ln_kernel<4096, bf16><<<dim3(MC), blk, 0, stream>>>(HS, fg, fb, HS, MC);
    gemm_bt<bf16, float><<<g1c, blk, 0, stream>>>(HS, w3w, w3b, x1, oc, MC, D, HD, 1);
  }
}

// Round 5
// 2937.614 us; speedup vs baseline: 2.4526x; 2.4526x over previous
//
#include <hip/hip_runtime.h>
#include <stdint.h>

typedef __bf16 bf16;
typedef __attribute__((ext_vector_type(8))) __bf16 bf16x8;
typedef __attribute__((ext_vector_type(4))) float floatx4;

__device__ inline float bflo(uint32_t u){ union{uint32_t v; float f;} t; t.v = u << 16; return t.f; }
__device__ inline float bfhi(uint32_t u){ union{uint32_t v; float f;} t; t.v = u & 0xffff0000u; return t.f; }
__device__ inline uint32_t pack2(float a, float b){ union{ bf16 h[2]; uint32_t u; } t; t.h[0]=(bf16)a; t.h[1]=(bf16)b; return t.u; }

__device__ inline void load4(const bf16* p, float* x){
  uint2 u = *(const uint2*)p; x[0]=bflo(u.x); x[1]=bfhi(u.x); x[2]=bflo(u.y); x[3]=bfhi(u.y);
}
__device__ inline void load4(const float* p, float* x){
  float4 u = *(const float4*)p; x[0]=u.x; x[1]=u.y; x[2]=u.z; x[3]=u.w;
}

// ---------------- LayerNorm (row-per-block, width W). In-place safe (row loaded to regs first). ----------------
template<int W, typename TIN>
__global__ __launch_bounds__(256) void ln_kernel(const TIN* in, const float* __restrict__ g,
                                                 const float* __restrict__ bb, bf16* out, int M)
{
  constexpr int E = W / 256;
  int row = blockIdx.x; if (row >= M) return;
  int tid = threadIdx.x;
  const TIN* rp = in + (size_t)row * W + tid * E;
  float x[E];
  #pragma unroll
  for (int j = 0; j < E; j += 4) load4(rp + j, &x[j]);
  float s = 0.f, ss = 0.f;
  #pragma unroll
  for (int e = 0; e < E; e++){ s += x[e]; ss += x[e]*x[e]; }
  #pragma unroll
  for (int k = 32; k >= 1; k >>= 1){ s += __shfl_xor(s, k, 64); ss += __shfl_xor(ss, k, 64); }
  __shared__ float rs_[4], rq_[4];
  if ((tid & 63) == 0){ rs_[tid >> 6] = s; rq_[tid >> 6] = ss; }
  __syncthreads();
  s = rs_[0]+rs_[1]+rs_[2]+rs_[3]; ss = rq_[0]+rq_[1]+rq_[2]+rq_[3];
  float mean = s * (1.0f / W);
  float var  = ss * (1.0f / W) - mean * mean;
  float rinv = rsqrtf(var + 1e-5f);
  bf16* op = out + (size_t)row * W + tid * E;
  const float* gp = g + tid * E;
  const float* bp = bb + tid * E;
  #pragma unroll
  for (int j = 0; j < E; j += 4){
    float gv[4], bv[4];
    load4(gp + j, gv); load4(bp + j, bv);
    float y0 = (x[j]  -mean)*rinv*gv[0] + bv[0];
    float y1 = (x[j+1]-mean)*rinv*gv[1] + bv[1];
    float y2 = (x[j+2]-mean)*rinv*gv[2] + bv[2];
    float y3 = (x[j+3]-mean)*rinv*gv[3] + bv[3];
    uint2 o; o.x = pack2(y0, y1); o.y = pack2(y2, y3);
    *(uint2*)(op + j) = o;
  }
}

// ---------------- NT GEMM: C[M,N] = A[M,K](bf16) @ B[N,K]^T(f32->bf16) + bias(f32), fused epilogues ----------------
// mode 0: +bias ; mode 1: +bias+extra[m,n] ; mode 2: silu(extra[m,n]) * (acc+bias)   [extra may alias C]
template<typename TE, typename TC>
__global__ __launch_bounds__(256) void gemm_bt(const bf16* __restrict__ A, const float* __restrict__ Bw,
                                               const float* __restrict__ bias, const TE* extra,
                                               TC* C, int M, int N, int K, int mode)
{
  __shared__ __align__(16) bf16 As[128*32];
  __shared__ __align__(16) bf16 Bs[128*32];
  int tid = threadIdx.x;
  int lane = tid & 63, wave = tid >> 6;
  int l16 = lane & 15, quad = lane >> 4;
  int wm = wave >> 1, wn = wave & 1;
  int m0 = blockIdx.y * 128, n0 = blockIdx.x * 128;
  floatx4 acc[4][4];
  #pragma unroll
  for (int i = 0; i < 4; i++)
    #pragma unroll
    for (int j = 0; j < 4; j++) acc[i][j] = (floatx4){0.f,0.f,0.f,0.f};
  int nk = K >> 5;
  uint4 ar[2];
  float4 br0[2], br1[2];
  int rowA[2], colA[2];
  #pragma unroll
  for (int rr = 0; rr < 2; rr++){ int lin = rr*256 + tid; rowA[rr] = lin >> 2; colA[rr] = (lin & 3) * 8; }
  auto prefetch = [&](int kt){
    #pragma unroll
    for (int rr = 0; rr < 2; rr++){
      size_t ka = (size_t)min(m0 + rowA[rr], M-1) * K + kt*32 + colA[rr];
      ar[rr] = *(const uint4*)(A + ka);
      const float* bp = Bw + (size_t)min(n0 + rowA[rr], N-1) * K + kt*32 + colA[rr];
      br0[rr] = *(const float4*)(bp);
      br1[rr] = *(const float4*)(bp + 4);
    }
  };
  prefetch(0);
  int kt = 0;
  while (true){
    __syncthreads();
    #pragma unroll
    for (int rr = 0; rr < 2; rr++){
      *(uint4*)&As[rowA[rr]*32 + colA[rr]] = ar[rr];
      union { uint4 q; bf16 h[8]; } pk;
      pk.h[0]=(bf16)br0[rr].x; pk.h[1]=(bf16)br0[rr].y; pk.h[2]=(bf16)br0[rr].z; pk.h[3]=(bf16)br0[rr].w;
      pk.h[4]=(bf16)br1[rr].x; pk.h[5]=(bf16)br1[rr].y; pk.h[6]=(bf16)br1[rr].z; pk.h[7]=(bf16)br1[rr].w;
      *(uint4*)&Bs[rowA[rr]*32 + colA[rr]] = pk.q;
    }
    __syncthreads();
    ++kt;
    bool more = kt < nk;
    if (more) prefetch(kt);
    bf16x8 af[4], bfv[4];
    #pragma unroll
    for (int i = 0; i < 4; i++) af[i]  = *(const bf16x8*)&As[(wm*64 + i*16 + l16)*32 + quad*8];
    #pragma unroll
    for (int j = 0; j < 4; j++) bfv[j] = *(const bf16x8*)&Bs[(wn*64 + j*16 + l16)*32 + quad*8];
    #pragma unroll
    for (int i = 0; i < 4; i++)
      #pragma unroll
      for (int j = 0; j < 4; j++)
        acc[i][j] = __builtin_amdgcn_mfma_f32_16x16x32_bf16(af[i], bfv[j], acc[i][j], 0, 0, 0);
    if (!more) break;
  }
  #pragma unroll
  for (int i = 0; i < 4; i++){
    int gmb = m0 + wm*64 + i*16 + quad*4;
    #pragma unroll
    for (int j = 0; j < 4; j++){
      int gn = n0 + wn*64 + j*16 + l16;
      float bv = bias ? bias[gn] : 0.f;
      #pragma unroll
      for (int r = 0; r < 4; r++){
        int gm = gmb + r;
        if (gm < M){
          float v = acc[i][j][r] + bv;
          if (mode == 1) v += (float)extra[(size_t)gm * N + gn];
          else if (mode == 2){ float a = (float)extra[(size_t)gm * N + gn]; v *= a / (1.f + __expf(-a)); }
          C[(size_t)gm * N + gn] = (TC)v;
        }
      }
    }
  }
}

// ---------------- RoPE (in-place on q and k buffers (bf16), tokens 1..256, all dims) ----------------
__global__ __launch_bounds__(256) void rope_kernel(bf16* __restrict__ q, bf16* __restrict__ k,
                                                   const float* __restrict__ cs, const float* __restrict__ sn)
{
  uint32_t i = blockIdx.x * 256u + threadIdx.x;   // 64*256*512 pairs
  int d0 = (int)(i & 511) * 2;
  int tok = (int)((i >> 9) & 255);
  int b = (int)(i >> 17);
  int j = d0 & 63;                                // dim within 64-wide head
  float c0 = cs[tok*64 + j], c1 = cs[tok*64 + j + 1];
  float s0 = sn[tok*64 + j], s1 = sn[tok*64 + j + 1];
  size_t off = ((size_t)(b*257 + tok + 1)) * 1024 + d0;
  uint32_t uq = *(const uint32_t*)(q + off);
  float x0 = bflo(uq), x1 = bfhi(uq);
  *(uint32_t*)(q + off) = pack2(x0*c0 - x1*s0, x1*c1 + x0*s1);
  uint32_t uk = *(const uint32_t*)(k + off);
  float y0 = bflo(uk), y1 = bfhi(uk);
  *(uint32_t*)(k + off) = pack2(y0*c0 - y1*s0, y1*c1 + y0*s1);
}

// ---------------- attention: one block per (b,h,qtile); flash-style over 2 KV chunks of 144 ----------------
__global__ __launch_bounds__(256) void attn_kernel(const bf16* __restrict__ Q, const bf16* __restrict__ Kg,
                                                   const bf16* __restrict__ Vg, const float* __restrict__ tab,
                                                   bf16* __restrict__ AO)
{
  __shared__ __align__(16) bf16 Kc[144*64];      // 18432 B
  __shared__ __align__(16) bf16 Vt[64*160];      // 20480 B  (V^T chunk, tok padded to 160)
  __shared__ __align__(16) float S[16*160];      // 10240 B
  __shared__ __align__(16) bf16 P[16*160];       //  5120 B
  __shared__ float mrow[16], lrow[16], arow[16];
  int id = blockIdx.x;
  int qt = id % 17; int rest = id / 17;
  int h = rest & 15; int b = rest >> 4;
  int tid = threadIdx.x; int wave = tid >> 6; int lane = tid & 63;
  int l16 = lane & 15, quad = lane >> 4;
  size_t base = ((size_t)b * 257) * 1024 + h * 64;
  int q0 = qt * 16;
  int tokA = min(q0 + l16, 256);
  const bf16* qp = Q + base + (size_t)tokA * 1024;
  bf16x8 a0 = *(const bf16x8*)(qp + quad*8);
  bf16x8 a1 = *(const bf16x8*)(qp + 32 + quad*8);
  floatx4 o = (floatx4){0.f,0.f,0.f,0.f};
  if (tid < 16){ mrow[tid] = -1e30f; lrow[tid] = 0.f; }
  for (int ch = 0; ch < 2; ch++){
    int t0 = ch * 144;
    __syncthreads();   // previous PV done (and init visible) before restaging
    for (int i = tid; i < 144*8; i += 256){
      int row = i >> 3, c8 = (i & 7) * 8;
      int tok = t0 + row;
      uint4 u = make_uint4(0,0,0,0);
      if (tok <= 256) u = *(const uint4*)(Kg + base + (size_t)tok*1024 + c8);
      *(uint4*)&Kc[row*64 + c8] = u;
    }
    for (int i = tid; i < 160*8; i += 256){
      int trow = i >> 3, c8 = (i & 7) * 8;
      int tok = t0 + trow;
      uint4 u = make_uint4(0,0,0,0);
      if (trow < 144 && tok <= 256) u = *(const uint4*)(Vg + base + (size_t)tok*1024 + c8);
      union { uint4 q4; bf16 h8[8]; } tmp; tmp.q4 = u;
      #pragma unroll
      for (int jj = 0; jj < 8; jj++) Vt[(c8 + jj)*160 + trow] = tmp.h8[jj];
    }
    __syncthreads();
    // S = Qtile @ Kc^T  (waves split over 9 kv sub-tiles)
    for (int nt = wave; nt < 9; nt += 4){
      int kr = nt*16 + l16;
      bf16x8 b0 = *(const bf16x8*)&Kc[kr*64 + quad*8];
      bf16x8 b1 = *(const bf16x8*)&Kc[kr*64 + 32 + quad*8];
      floatx4 c = (floatx4){0.f,0.f,0.f,0.f};
      c = __builtin_amdgcn_mfma_f32_16x16x32_bf16(a0, b0, c, 0, 0, 0);
      c = __builtin_amdgcn_mfma_f32_16x16x32_bf16(a1, b1, c, 0, 0, 0);
      #pragma unroll
      for (int r = 0; r < 4; r++) S[(quad*4 + r)*160 + nt*16 + l16] = c[r];
    }
    __syncthreads();
    // online softmax partial (16 threads per q row)
    {
      int r = tid >> 4, li = tid & 15;
      int qg = q0 + r; bool vrow = qg <= 256;
      float vals[10]; float mc = -1e30f;
      #pragma unroll
      for (int jj = 0; jj < 10; jj++){
        int c = li + 16*jj; int kg = t0 + c;
        float sv = -1e30f;
        if (vrow && c < 144 && kg <= 256){
          int idx;
          if (qg == 0 && kg == 0) idx = 963;
          else if (qg == 0) idx = 961;
          else if (kg == 0) idx = 962;
          else { int p = qg - 1, pk = kg - 1;
                 idx = ((p >> 4) - (pk >> 4) + 15) * 31 + ((p & 15) - (pk & 15) + 15); }
          sv = S[r*160 + c] * 0.125f + tab[idx*16 + h];
        }
        vals[jj] = sv; mc = fmaxf(mc, sv);
      }
      #pragma unroll
      for (int k = 8; k >= 1; k >>= 1) mc = fmaxf(mc, __shfl_xor(mc, k, 16));
      float mold = mrow[r];
      float mnew = fmaxf(mold, mc);
      float alpha = __expf(mold - mnew);
      float sum = 0.f;
      #pragma unroll
      for (int jj = 0; jj < 10; jj++){
        float p = (vals[jj] > -1e29f) ? __expf(vals[jj] - mnew) : 0.f;
        sum += p;
        P[r*160 + li + 16*jj] = (bf16)p;
      }
      #pragma unroll
      for (int k = 8; k >= 1; k >>= 1) sum += __shfl_xor(sum, k, 16);
      if (li == 0){ mrow[r] = mnew; lrow[r] = lrow[r]*alpha + sum; arow[r] = alpha; }
    }
    __syncthreads();
    // rescale + PV
    #pragma unroll
    for (int r2 = 0; r2 < 4; r2++) o[r2] *= arow[quad*4 + r2];
    #pragma unroll
    for (int ks = 0; ks < 5; ks++){
      bf16x8 pa = *(const bf16x8*)&P[l16*160 + ks*32 + quad*8];
      bf16x8 vb = *(const bf16x8*)&Vt[(wave*16 + l16)*160 + ks*32 + quad*8];
      o = __builtin_amdgcn_mfma_f32_16x16x32_bf16(pa, vb, o, 0, 0, 0);
    }
  }
  #pragma unroll
  for (int r2 = 0; r2 < 4; r2++){
    int qr = q0 + quad*4 + r2;
    if (qr <= 256){
      float inv = 1.0f / lrow[quad*4 + r2];
      AO[base + (size_t)qr*1024 + wave*16 + l16] = (bf16)(o[r2] * inv);
    }
  }
}

extern "C" void kernel_launch(void* const* d_in, const int* in_sizes, int n_in,
                              void* d_out, int out_size, void* d_ws, size_t ws_size,
                              hipStream_t stream)
{
  (void)in_sizes; (void)n_in; (void)out_size; (void)ws_size;
  const float* x    = (const float*)d_in[0];
  const float* rc   = (const float*)d_in[1];
  const float* rsn  = (const float*)d_in[2];
  const float* q_w  = (const float*)d_in[3];
  const float* q_b  = (const float*)d_in[4];
  const float* k_w  = (const float*)d_in[5];
  const float* v_w  = (const float*)d_in[6];
  const float* v_b  = (const float*)d_in[7];
  const float* tab  = (const float*)d_in[8];
  const float* ig   = (const float*)d_in[9];
  const float* ib   = (const float*)d_in[10];
  const float* pw   = (const float*)d_in[11];
  const float* pb   = (const float*)d_in[12];
  const float* n1g  = (const float*)d_in[13];
  const float* n1b  = (const float*)d_in[14];
  const float* n2g  = (const float*)d_in[15];
  const float* n2b  = (const float*)d_in[16];
  const float* w1w  = (const float*)d_in[17];
  const float* w1b  = (const float*)d_in[18];
  const float* w2w  = (const float*)d_in[19];
  const float* w2b  = (const float*)d_in[20];
  const float* fg   = (const float*)d_in[21];
  const float* fb   = (const float*)d_in[22];
  const float* w3w  = (const float*)d_in[23];
  const float* w3b  = (const float*)d_in[24];

  const int M = 64 * 257;        // 16448
  const int D = 1024, HD = 4096;
  char* ws = (char*)d_ws;
  const size_t CHB = (size_t)M * D * 2;          // 33,685,504 B (bf16 channel buffer)
  // total ws used: 4*CHB = 134,742,016 B
  bf16* B0 = (bf16*)(ws);
  bf16* B1 = (bf16*)(ws + CHB);
  bf16* B2 = (bf16*)(ws + 2*CHB);
  bf16* B3 = (bf16*)(ws + 3*CHB);
  bf16* XN  = B0;          // LN1 out
  bf16* Qb  = B1;
  bf16* Kbf = B2;
  bf16* Vbf = B3;
  bf16* AO  = B0;          // XN dead after V GEMM
  bf16* AOL = B1;          // Q dead after attention
  bf16* X1  = B2;          // K dead after attention
  bf16* XN2 = B3;          // V dead after LN2
  bf16* HS  = B0;          // 2*CHB region (B0+B1): AO/AOL dead — per-FFN-chunk hidden
  float* OUT = (float*)d_out;

  dim3 blk(256);
  dim3 g1(D/128, (M + 127)/128);

  ln_kernel<1024, float><<<dim3(M), blk, 0, stream>>>(x, n1g, n1b, XN, M);
  gemm_bt<bf16, bf16><<<g1, blk, 0, stream>>>(XN, q_w, q_b, (const bf16*)nullptr, Qb, M, D, D, 0);
  gemm_bt<bf16, bf16><<<g1, blk, 0, stream>>>(XN, k_w, nullptr, (const bf16*)nullptr, Kbf, M, D, D, 0);
  gemm_bt<bf16, bf16><<<g1, blk, 0, stream>>>(XN, v_w, v_b, (const bf16*)nullptr, Vbf, M, D, D, 0);
  rope_kernel<<<dim3(64*256*512/256), blk, 0, stream>>>(Qb, Kbf, rc, rsn);
  attn_kernel<<<dim3(64*16*17), blk, 0, stream>>>(Qb, Kbf, Vbf, tab, AO);
  ln_kernel<1024, bf16><<<dim3(M), blk, 0, stream>>>(AO, ig, ib, AOL, M);
  gemm_bt<float, bf16><<<g1, blk, 0, stream>>>(AOL, pw, pb, x, X1, M, D, D, 1);
  ln_kernel<1024, bf16><<<dim3(M), blk, 0, stream>>>(X1, n2g, n2b, XN2, M);

  // FFN in two M/2 row-chunks so hidden fits in 2*CHB
  const int MC = M / 2;                       // 8224
  dim3 g2(HD/128, (MC + 127)/128);
  dim3 g1c(D/128, (MC + 127)/128);
  for (int c = 0; c < 2; c++){
    const bf16* a2 = XN2 + (size_t)c * MC * D;
    const bf16* x1 = X1  + (size_t)c * MC * D;
    float*      oc = OUT + (size_t)c * MC * D;
    gemm_bt<bf16, bf16><<<g2, blk, 0, stream>>>(a2, w1w, w1b, (const bf16*)nullptr, HS, MC, HD, D, 0);
    gemm_bt<bf16, bf16><<<g2, blk, 0, stream>>>(a2, w2w, w2b, HS, HS, MC, HD, D, 2);
    ln_kernel<4096, bf16><<<dim3(MC), blk, 0, stream>>>(HS, fg, fb, HS, MC);
    gemm_bt<bf16, float><<<g1c, blk, 0, stream>>>(HS, w3w, w3b, x1, oc, MC, D, HD, 1);
  }
}